// Round 11
// baseline (5287.474 us; speedup 1.0000x reference)
//
#include <hip/hip_runtime.h>
#include <cstdint>
#include <cstddef>

// B=256, T=512, D=64, H=256, G=1024. Two-layer LSTM + FC.
// Pipeline (R9): one mega dispatch per d=0..18:
//   blocks 0-7: rec L0 chunk d-1 | 8-15: rec L1 chunk d-3
//   blocks 16-271: gemmA xp0(d) from x | 272-527: gemmB xp1(d-2) from h0c
// R11: all W/xp accesses lane-contiguous (frag-order W, rec-order xp).
// R14/R15: two independent batch-tiles per rec block (act(A) overlaps
// MFMA(B); W fragments amortized across both tiles). Correctness verified.
// R16: fix R15's spill storm (live set ~230 vs 128 arch VGPRs). wreg is
// GONE: kf2-7 streamed from L2 at their MFMAs (t-invariant, L2-hot, 1KB
// contiguous per wave inst; both tiles share each fragment). Arch live set
// ~95 regs + 64 AGPR acc -> fits 2 waves/SIMD with zero scratch.
#define GATES 1024
#define SEQT  512
#define TCH   32
#define NCH   16
#define XPSTEP 262144           // elements per timestep in rec-order xp
#define XPCH  8388608           // elements per chunk xp buffer (16 MB)
#define H0CCH 2097152           // elements per chunk h0c buffer (4 MB)

using u16 = unsigned short;
using bf16x8 = __attribute__((ext_vector_type(8))) short;   // 8 bf16 = 4 VGPRs
using f32x4  = __attribute__((ext_vector_type(4))) float;

__device__ __forceinline__ float bf2f(u16 u) {
    union { float f; unsigned int i; } v; v.i = ((unsigned int)u) << 16; return v.f;
}
__device__ __forceinline__ u16 f2bf(float f) {
    union { float f; unsigned int i; } v; v.f = f;
    unsigned int r = v.i + 0x7FFFu + ((v.i >> 16) & 1u);   // RNE
    return (u16)(r >> 16);
}
// overflow-safe fast activations (v_exp + v_rcp, ~1 ulp)
__device__ __forceinline__ float sigm(float x) {
    return __builtin_amdgcn_rcpf(1.f + __expf(-x));
}
__device__ __forceinline__ float tanh_f(float x) {
    return 1.f - 2.f * __builtin_amdgcn_rcpf(1.f + __expf(2.f * x));
}

// ---------------- prep ----------------
__global__ void k_conv(const float* __restrict__ src, u16* __restrict__ dst, int n) {
    int i = blockIdx.x * 256 + threadIdx.x;
    if (i < n) dst[i] = f2bf(src[i]);
}
__global__ void k_bias(const float* __restrict__ a, const float* __restrict__ b,
                       float* __restrict__ o, int n) {
    int i = blockIdx.x * 256 + threadIdx.x;
    if (i < n) o[i] = a[i] + b[i];
}
// W_hh [1024][256] -> frag-order (8-wave rec): Wf[((wave*8+kf)*8+f)*512 + lane*8 + e]
// row = (f>>1)*256 + wave*32 + (f&1)*16 + (lane&15), col = kf*32 + (lane>>4)*8 + e
__global__ void k_wshuf(const u16* __restrict__ src, u16* __restrict__ dst) {
    int idx = blockIdx.x;                 // 512 blocks = (wave*8+kf)*8+f
    int f = idx & 7, kf = (idx >> 3) & 7, wave = idx >> 6;
    int lane = threadIdx.x;               // 64 threads
    int ml = lane & 15, q = lane >> 4;
    int row = (f >> 1) * 256 + wave * 32 + (f & 1) * 16 + ml;
    int col = kf * 32 + q * 8;
    *(bf16x8*)&dst[(size_t)idx * 512 + lane * 8] =
        *(const bf16x8*)&src[(size_t)row * 256 + col];
}

// ---------------- mega: rec (16 blocks) + gemmA (256) + gemmB (256) --------
__global__ __attribute__((amdgpu_flat_work_group_size(512, 512),
                          amdgpu_waves_per_eu(2, 2))) void mega(
    const float* __restrict__ x,
    const u16* __restrict__ Wih0b, const u16* __restrict__ Whh0f,
    const u16* __restrict__ Wih1b, const u16* __restrict__ Whh1f,
    const float* __restrict__ bias0, const float* __restrict__ bias1,
    u16* __restrict__ xp0base, u16* __restrict__ xp1base,
    u16* __restrict__ h0cbase, float* __restrict__ hlast,
    u16* __restrict__ hs0, float* __restrict__ cs0,
    u16* __restrict__ hs1, float* __restrict__ cs1, int d)
{
    __shared__ __align__(16) u16 SMEM[81920];   // 163840 B, overlaid per role
    const int tid = threadIdx.x;

    if (blockIdx.x < 16) {
        // ========== rec: 8 waves, 2 tiles of 16 rows, wave owns 128 gates ==
        const int L   = blockIdx.x >> 3;
        const int blk = blockIdx.x & 7;
        const int chunk = L ? d - 3 : d - 1;
        if (chunk < 0 || chunk >= NCH) return;
        const u16* xp = (L ? xp1base : xp0base) + (size_t)(chunk & 1) * XPCH;
        const u16* Wf = L ? Whh1f : Whh0f;
        u16*  hs = L ? hs1 : hs0;
        float* cs = L ? cs1 : cs0;
        u16* h0c = h0cbase + (size_t)(chunk & 1) * H0CCH;
        const int init = (chunk == 0);

        u16* WL  = SMEM;            // 131072 B (kf0-1, per-wave frag-order)
        u16* hAu = SMEM + 65536;    // 32768 B: [tile][buf][16][256] swizzled

        const int wave = tid >> 6, lane = tid & 63;
        const int ml   = lane & 15, q = lane >> 4;
        const int ub   = wave * 32;
        const int bb0  = blk * 32;           // tile T rows: bb0 + T*16

        // swizzled hA u16-index: byte = tile*16384+buf*8192+row*512+colb,
        // byte ^= (row&7)<<4  (same mapping for writes and b128 reads)
        auto hidx = [](int tile, int buf, int row, int colb) -> int {
            int byte = tile * 16384 + buf * 8192 + row * 512 + colb;
            return (byte ^ ((row & 7) << 4)) >> 1;
        };

        const u16* wfb = Wf + (size_t)wave * 32768 + lane * 8;
        const int wlb = (wave * 1024 + lane) * 8;

        // stage W kf0-1 into LDS (contiguous 1KB per wave inst)
        #pragma unroll
        for (int kf = 0; kf < 2; ++kf)
            #pragma unroll
            for (int f = 0; f < 8; ++f)
                *(bf16x8*)&WL[wlb + (kf * 8 + f) * 512] =
                    *(const bf16x8*)(wfb + (kf * 8 + f) * 512);

        float cA[8], cB[8];
        if (init) {
            for (int i = tid; i < 16384; i += 512) hAu[i] = 0;
            #pragma unroll
            for (int i = 0; i < 8; ++i) { cA[i] = 0.f; cB[i] = 0.f; }
        } else {
            int m = tid >> 5, j0 = (tid & 31) * 8;
            *(bf16x8*)&hAu[hidx(0, 0, m, j0 * 2)] =
                *(const bf16x8*)&hs[(size_t)(bb0 + m) * 256 + j0];
            *(bf16x8*)&hAu[hidx(1, 0, m, j0 * 2)] =
                *(const bf16x8*)&hs[(size_t)(bb0 + 16 + m) * 256 + j0];
            #pragma unroll
            for (int s = 0; s < 2; ++s)
                #pragma unroll
                for (int r = 0; r < 4; ++r) {
                    cA[s * 4 + r] = cs[(size_t)(bb0 + q * 4 + r) * 256 + ub + s * 16 + ml];
                    cB[s * 4 + r] = cs[(size_t)(bb0 + 16 + q * 4 + r) * 256 + ub + s * 16 + ml];
                }
        }

        // xp (R11 layout): [t][oblk=blk*2+T][gi][tid][8]
        const u16* xpA = xp + (size_t)(blk * 2 + 0) * 16384 + (size_t)tid * 8;
        const u16* xpB = xp + (size_t)(blk * 2 + 1) * 16384 + (size_t)tid * 8;
        const int m_st = tid >> 5;
        const int j_st = (tid & 31) * 8;

        __syncthreads();

        for (int t = 0; t < TCH; ++t) {
            const int br = t & 1, bw = br ^ 1;

            bf16x8 xvA[4], xvB[4];
            #pragma unroll
            for (int gi = 0; gi < 4; ++gi) {
                xvA[gi] = *(const bf16x8*)(xpA + gi * 4096);
                xvB[gi] = *(const bf16x8*)(xpB + gi * 4096);
            }

            f32x4 accA[4][2], accB[4][2];
            #pragma unroll
            for (int gi = 0; gi < 4; ++gi)
                #pragma unroll
                for (int s = 0; s < 2; ++s) {
                    accA[gi][s] = (f32x4)0.f;
                    accB[gi][s] = (f32x4)0.f;
                }

            // 8 kf x 8 f; kf0-1 from LDS, kf2-7 streamed from L2 (t-invariant
            // addresses, L2-hot). Each W fragment feeds BOTH tiles' MFMAs.
            #pragma unroll
            for (int kf = 0; kf < 8; ++kf) {
                bf16x8 a0 = *(const bf16x8*)&hAu[hidx(0, br, ml, kf * 64 + q * 16)];
                bf16x8 a1 = *(const bf16x8*)&hAu[hidx(1, br, ml, kf * 64 + q * 16)];
                #pragma unroll
                for (int f = 0; f < 8; ++f) {
                    bf16x8 b;
                    if (kf < 2) b = *(const bf16x8*)&WL[wlb + (kf * 8 + f) * 512];
                    else        b = *(const bf16x8*)(wfb + (kf * 8 + f) * 512);
                    accA[f >> 1][f & 1] = __builtin_amdgcn_mfma_f32_16x16x32_bf16(
                        a0, b, accA[f >> 1][f & 1], 0, 0, 0);
                    accB[f >> 1][f & 1] = __builtin_amdgcn_mfma_f32_16x16x32_bf16(
                        a1, b, accB[f >> 1][f & 1], 0, 0, 0);
                }
            }

            // activations + cell update, tile A then tile B (independent --
            // act(A) issues under MFMA(B)/LDS latency; compiler interleaves)
            #pragma unroll
            for (int s = 0; s < 2; ++s) {
                const int j = ub + s * 16 + ml;
                float hv[4];
                #pragma unroll
                for (int r = 0; r < 4; ++r) {
                    float ig = sigm(accA[0][s][r] + bf2f((u16)xvA[0][s * 4 + r]));
                    float fg = sigm(accA[1][s][r] + bf2f((u16)xvA[1][s * 4 + r]));
                    float gg = tanh_f(accA[2][s][r] + bf2f((u16)xvA[2][s * 4 + r]));
                    float og = sigm(accA[3][s][r] + bf2f((u16)xvA[3][s * 4 + r]));
                    float cc = fg * cA[s * 4 + r] + ig * gg;
                    cA[s * 4 + r] = cc;
                    hv[r] = og * tanh_f(cc);
                }
                unsigned p01, p23;
                asm("v_cvt_pk_bf16_f32 %0, %1, %2" : "=v"(p01) : "v"(hv[0]), "v"(hv[1]));
                asm("v_cvt_pk_bf16_f32 %0, %1, %2" : "=v"(p23) : "v"(hv[2]), "v"(hv[3]));
                hAu[hidx(0, bw, q * 4 + 0, j * 2)] = (u16)p01;
                hAu[hidx(0, bw, q * 4 + 1, j * 2)] = (u16)(p01 >> 16);
                hAu[hidx(0, bw, q * 4 + 2, j * 2)] = (u16)p23;
                hAu[hidx(0, bw, q * 4 + 3, j * 2)] = (u16)(p23 >> 16);
                if (L == 1 && chunk == NCH - 1 && t == TCH - 1) {
                    #pragma unroll
                    for (int r = 0; r < 4; ++r)
                        hlast[(size_t)(bb0 + q * 4 + r) * 256 + j] = hv[r];
                }
            }
            #pragma unroll
            for (int s = 0; s < 2; ++s) {
                const int j = ub + s * 16 + ml;
                float hv[4];
                #pragma unroll
                for (int r = 0; r < 4; ++r) {
                    float ig = sigm(accB[0][s][r] + bf2f((u16)xvB[0][s * 4 + r]));
                    float fg = sigm(accB[1][s][r] + bf2f((u16)xvB[1][s * 4 + r]));
                    float gg = tanh_f(accB[2][s][r] + bf2f((u16)xvB[2][s * 4 + r]));
                    float og = sigm(accB[3][s][r] + bf2f((u16)xvB[3][s * 4 + r]));
                    float cc = fg * cB[s * 4 + r] + ig * gg;
                    cB[s * 4 + r] = cc;
                    hv[r] = og * tanh_f(cc);
                }
                unsigned p01, p23;
                asm("v_cvt_pk_bf16_f32 %0, %1, %2" : "=v"(p01) : "v"(hv[0]), "v"(hv[1]));
                asm("v_cvt_pk_bf16_f32 %0, %1, %2" : "=v"(p23) : "v"(hv[2]), "v"(hv[3]));
                hAu[hidx(1, bw, q * 4 + 0, j * 2)] = (u16)p01;
                hAu[hidx(1, bw, q * 4 + 1, j * 2)] = (u16)(p01 >> 16);
                hAu[hidx(1, bw, q * 4 + 2, j * 2)] = (u16)p23;
                hAu[hidx(1, bw, q * 4 + 3, j * 2)] = (u16)(p23 >> 16);
                if (L == 1 && chunk == NCH - 1 && t == TCH - 1) {
                    #pragma unroll
                    for (int r = 0; r < 4; ++r)
                        hlast[(size_t)(bb0 + 16 + q * 4 + r) * 256 + j] = hv[r];
                }
            }
            xpA += XPSTEP; xpB += XPSTEP;

            // publish h(t+1): only hA ds ops gate the barrier
            asm volatile("s_waitcnt lgkmcnt(0)\n\ts_barrier" ::: "memory");

            if (L == 0) {
                *(bf16x8*)&h0c[((size_t)t * 256 + bb0 + m_st) * 256 + j_st] =
                    *(const bf16x8*)&hAu[hidx(0, bw, m_st, j_st * 2)];
                *(bf16x8*)&h0c[((size_t)t * 256 + bb0 + 16 + m_st) * 256 + j_st] =
                    *(const bf16x8*)&hAu[hidx(1, bw, m_st, j_st * 2)];
            }
        }

        // persist state (TCH even -> final h is in buf 0)
        #pragma unroll
        for (int s = 0; s < 2; ++s)
            #pragma unroll
            for (int r = 0; r < 4; ++r) {
                cs[(size_t)(bb0 + q * 4 + r) * 256 + ub + s * 16 + ml] = cA[s * 4 + r];
                cs[(size_t)(bb0 + 16 + q * 4 + r) * 256 + ub + s * 16 + ml] = cB[s * 4 + r];
            }
        {
            int m = tid >> 5, j0 = (tid & 31) * 8;
            *(bf16x8*)&hs[(size_t)(bb0 + m) * 256 + j0] =
                *(const bf16x8*)&hAu[hidx(0, 0, m, j0 * 2)];
            *(bf16x8*)&hs[(size_t)(bb0 + 16 + m) * 256 + j0] =
                *(const bf16x8*)&hAu[hidx(1, 0, m, j0 * 2)];
        }
        return;
    }

    // =================== gemm (A: xp0 from x; B: xp1 from h0c) ===================
    const int role = (blockIdx.x < 272) ? 0 : 1;
    const int bid  = blockIdx.x - (role ? 272 : 16);
    const int chunk = role ? d - 2 : d;
    if (chunk < 0 || chunk >= NCH) return;

    const int K = role ? 256 : 64;
    const u16* Wp = role ? Wih1b : Wih0b;
    const float* bias = role ? bias1 : bias0;
    u16* out = (role ? xp1base : xp0base) + (size_t)(chunk & 1) * XPCH;
    const u16* A1 = h0cbase + (size_t)(chunk & 1) * H0CCH;   // role B source

    u16 (*As)[40] = (u16 (*)[40])SMEM;            // [128][40]
    u16 (*Bs)[40] = (u16 (*)[40])(SMEM + 5120);   // [256][40]

    const int mb = bid >> 2, nb = bid & 3;
    const int n0 = nb * 256;
    const int wave = tid >> 6, lane = tid & 63;
    const int wm = wave >> 2, wn = wave & 3;      // 2 x 4 wave grid -> 128x256 tile
    const int ml = lane & 15, q = lane >> 4;
    const int tloc = mb >> 1;
    const int bbas = (mb & 1) * 128;
    const int tt = role ? tloc : chunk * TCH + tloc;

    f32x4 acc[4][4];
    #pragma unroll
    for (int mi = 0; mi < 4; ++mi)
        #pragma unroll
        for (int ni = 0; ni < 4; ++ni)
            acc[mi][ni] = (f32x4)0.f;

    const int nk = K >> 5;
    for (int kt = 0; kt < nk; ++kt) {
        __syncthreads();
        {
            int row = tid >> 2, kb = tid & 3;
            if (role) {
                *(uint4*)&As[row][kb * 8] = *(const uint4*)(
                    A1 + (size_t)tt * 65536 + (size_t)(bbas + row) * 256 + kt * 32 + kb * 8);
            } else {
                const float* xs = x + (size_t)(bbas + row) * 32768 + (size_t)tt * 64
                                    + kt * 32 + kb * 8;
                float4 fa = *(const float4*)xs;
                float4 fb = *(const float4*)(xs + 4);
                uint4 v;
                v.x = f2bf(fa.x) | ((unsigned)f2bf(fa.y) << 16);
                v.y = f2bf(fa.z) | ((unsigned)f2bf(fa.w) << 16);
                v.z = f2bf(fb.x) | ((unsigned)f2bf(fb.y) << 16);
                v.w = f2bf(fb.z) | ((unsigned)f2bf(fb.w) << 16);
                *(uint4*)&As[row][kb * 8] = v;
            }
            #pragma unroll
            for (int i = 0; i < 2; ++i) {
                int c2 = tid + i * 512, r2 = c2 >> 2, k2 = c2 & 3;
                *(uint4*)&Bs[r2][k2 * 8] = *(const uint4*)(
                    Wp + (size_t)(n0 + r2) * K + kt * 32 + k2 * 8);
            }
        }
        __syncthreads();
        bf16x8 af[4], bfr[4];
        #pragma unroll
        for (int mi = 0; mi < 4; ++mi)
            af[mi] = *(const bf16x8*)&As[wm * 64 + mi * 16 + ml][q * 8];
        #pragma unroll
        for (int ni = 0; ni < 4; ++ni)
            bfr[ni] = *(const bf16x8*)&Bs[wn * 64 + ni * 16 + ml][q * 8];
        #pragma unroll
        for (int mi = 0; mi < 4; ++mi)
            #pragma unroll
            for (int ni = 0; ni < 4; ++ni)
                acc[mi][ni] = __builtin_amdgcn_mfma_f32_16x16x32_bf16(
                    af[mi], bfr[ni], acc[mi][ni], 0, 0, 0);
    }

    // epilogue -> xp (R11 layout, VERIFIED form):
    // el = ((tloc*16+blk2)*4+gi)*512*8 ... = ((x)*512 + tid_r)*8 + s*4 + rr
    #pragma unroll
    for (int ni = 0; ni < 4; ++ni) {
        int gc = n0 + wn * 64 + ni * 16 + ml;
        int gi = gc >> 8, u = gc & 255;
        int wv = u >> 5, s = (u >> 4) & 1, mlr = u & 15;
        float bv = bias[gc];
        #pragma unroll
        for (int mi = 0; mi < 4; ++mi) {
            int rowbase = bbas + wm * 64 + mi * 16;        // multiple of 16
            int blk2 = rowbase >> 4;
            size_t el0 = ((size_t)((tloc * 16 + blk2) * 4 + gi) * 512
                          + wv * 64 + q * 16 + mlr) * 8 + s * 4;
            #pragma unroll
            for (int rr = 0; rr < 4; ++rr)
                out[el0 + rr] = f2bf(acc[mi][ni][rr] + bv);
        }
    }
}

// ---------------- FC head ----------------
__global__ void fc_k(const float* __restrict__ h, const float* __restrict__ w,
                     const float* __restrict__ b, float* __restrict__ out)
{
    int bb = blockIdx.x, lane = threadIdx.x;
    float s = 0.f;
    for (int j = lane; j < 256; j += 64) s += h[bb * 256 + j] * w[j];
    #pragma unroll
    for (int off = 32; off > 0; off >>= 1) s += __shfl_down(s, off);
    if (lane == 0) out[bb] = s + b[0];
}

extern "C" void kernel_launch(void* const* d_in, const int* in_sizes, int n_in,
                              void* d_out, int out_size, void* d_ws, size_t ws_size,
                              hipStream_t stream)
{
    const float* x    = (const float*)d_in[0];
    const float* Wih0 = (const float*)d_in[1];
    const float* Whh0 = (const float*)d_in[2];
    const float* bih0 = (const float*)d_in[3];
    const float* bhh0 = (const float*)d_in[4];
    const float* Wih1 = (const float*)d_in[5];
    const float* Whh1 = (const float*)d_in[6];
    const float* bih1 = (const float*)d_in[7];
    const float* bhh1 = (const float*)d_in[8];
    const float* fcw  = (const float*)d_in[9];
    const float* fcb  = (const float*)d_in[10];
    float* out = (float*)d_out;

    // workspace layout, total ~75.6 MB
    char* ws = (char*)d_ws;
    u16*   xp0b  = (u16*)(ws);                  // 33554432  (2 chunks)
    u16*   xp1b  = (u16*)(ws + 33554432);       // 33554432  (2 chunks)
    u16*   h0cb  = (u16*)(ws + 67108864);       //  8388608  (2 chunks)
    u16*   Wih0b = (u16*)(ws + 75497472);       //   131072
    u16*   Whh0b = (u16*)(ws + 75628544);       //   524288
    u16*   Wih1b = (u16*)(ws + 76152832);       //   524288
    u16*   Whh1b = (u16*)(ws + 76677120);       //   524288
    float* bias0 = (float*)(ws + 77201408);     //     4096
    float* bias1 = (float*)(ws + 77205504);     //     4096
    u16*   hs0   = (u16*)(ws + 77209600);       //   131072
    float* cs0   = (float*)(ws + 77340672);     //   262144
    u16*   hs1   = (u16*)(ws + 77602816);       //   131072
    float* cs1   = (float*)(ws + 77733888);     //   262144
    float* h1l   = (float*)(ws + 77996032);     //   262144
    u16*   Whh0f = (u16*)(ws + 78258176);       //   524288  frag-order W
    u16*   Whh1f = (u16*)(ws + 78782464);       //   524288

    k_conv<<<256,  256, 0, stream>>>(Wih0, Wih0b, 65536);
    k_conv<<<1024, 256, 0, stream>>>(Whh0, Whh0b, 262144);
    k_conv<<<1024, 256, 0, stream>>>(Wih1, Wih1b, 262144);
    k_conv<<<1024, 256, 0, stream>>>(Whh1, Whh1b, 262144);
    k_bias<<<4, 256, 0, stream>>>(bih0, bhh0, bias0, 1024);
    k_bias<<<4, 256, 0, stream>>>(bih1, bhh1, bias1, 1024);
    k_wshuf<<<512, 64, 0, stream>>>(Whh0b, Whh0f);
    k_wshuf<<<512, 64, 0, stream>>>(Whh1b, Whh1f);

    for (int d = 0; d <= NCH + 2; ++d)   // d = 0..18
        mega<<<528, 512, 0, stream>>>(x, Wih0b, Whh0f, Wih1b, Whh1f,
                                      bias0, bias1, xp0b, xp1b, h0cb, h1l,
                                      hs0, cs0, hs1, cs1, d);
    fc_k<<<256, 64, 0, stream>>>(h1l, fcw, fcb, out);
}

// Round 12
// 2201.678 us; speedup vs baseline: 2.4016x; 2.4016x over previous
//
#include <hip/hip_runtime.h>
#include <cstdint>
#include <cstddef>

// B=256, T=512, D=64, H=256, G=1024. Two-layer LSTM + FC.
// Pipeline (R9): one mega dispatch per d=0..18:
//   blocks 0-15: rec L0 chunk d-1 | 16-31: rec L1 chunk d-3
//   blocks 32-287: gemmA xp0(d) from x | 288-543: gemmB xp1(d-2) from h0c
// R11 (verified best, 2131us): all W/xp accesses lane-contiguous
// (frag-order W, rec-order xp); kf0-1 LDS, kf2-5 reg, kf6-7 streamed.
// R14-R16 (2-tile, 16 blocks): dead -- W-stream per CU doubled, 2.5x slower.
// R17: R11 exactly, plus wreg extended kf2-6 (160 regs; unified 256-reg
// budget @2 waves/SIMD holds ~244 live) -> only kf7 streamed per step.
// Halves the per-step L2 W-stream 128->64 KB/block. Clean A/B on the
// "W-stream is the remaining cost" hypothesis.
#define GATES 1024
#define SEQT  512
#define TCH   32
#define NCH   16
#define XPSTEP 262144           // elements per timestep in rec-order xp
#define XPCH  8388608           // elements per chunk xp buffer (16 MB)
#define H0CCH 2097152           // elements per chunk h0c buffer (4 MB)

using u16 = unsigned short;
using bf16x8 = __attribute__((ext_vector_type(8))) short;   // 8 bf16 = 4 VGPRs
using f32x4  = __attribute__((ext_vector_type(4))) float;

__device__ __forceinline__ float bf2f(u16 u) {
    union { float f; unsigned int i; } v; v.i = ((unsigned int)u) << 16; return v.f;
}
__device__ __forceinline__ u16 f2bf(float f) {
    union { float f; unsigned int i; } v; v.f = f;
    unsigned int r = v.i + 0x7FFFu + ((v.i >> 16) & 1u);   // RNE
    return (u16)(r >> 16);
}
// overflow-safe fast activations (v_exp + v_rcp, ~1 ulp)
__device__ __forceinline__ float sigm(float x) {
    return __builtin_amdgcn_rcpf(1.f + __expf(-x));
}
__device__ __forceinline__ float tanh_f(float x) {
    return 1.f - 2.f * __builtin_amdgcn_rcpf(1.f + __expf(2.f * x));
}

// ---------------- prep ----------------
__global__ void k_conv(const float* __restrict__ src, u16* __restrict__ dst, int n) {
    int i = blockIdx.x * 256 + threadIdx.x;
    if (i < n) dst[i] = f2bf(src[i]);
}
__global__ void k_bias(const float* __restrict__ a, const float* __restrict__ b,
                       float* __restrict__ o, int n) {
    int i = blockIdx.x * 256 + threadIdx.x;
    if (i < n) o[i] = a[i] + b[i];
}
// W_hh [1024][256] -> frag-order Wf[((wave*8+kf)*8+f)*512 + lane*8 + e]
// row = (f>>1)*256 + wave*32 + (f&1)*16 + (lane&15), col = kf*32 + (lane>>4)*8 + e
__global__ void k_wshuf(const u16* __restrict__ src, u16* __restrict__ dst) {
    int idx = blockIdx.x;                 // 512 blocks = (wave*8+kf)*8+f
    int f = idx & 7, kf = (idx >> 3) & 7, wave = idx >> 6;
    int lane = threadIdx.x;               // 64 threads
    int ml = lane & 15, q = lane >> 4;
    int row = (f >> 1) * 256 + wave * 32 + (f & 1) * 16 + ml;
    int col = kf * 32 + q * 8;
    *(bf16x8*)&dst[(size_t)idx * 512 + lane * 8] =
        *(const bf16x8*)&src[(size_t)row * 256 + col];
}

// ---------------- mega: rec (32 blocks) + gemmA (256) + gemmB (256) --------
__global__ __attribute__((amdgpu_flat_work_group_size(512, 512),
                          amdgpu_waves_per_eu(2, 2))) void mega(
    const float* __restrict__ x,
    const u16* __restrict__ Wih0b, const u16* __restrict__ Whh0f,
    const u16* __restrict__ Wih1b, const u16* __restrict__ Whh1f,
    const float* __restrict__ bias0, const float* __restrict__ bias1,
    u16* __restrict__ xp0base, u16* __restrict__ xp1base,
    u16* __restrict__ h0cbase, float* __restrict__ hlast,
    u16* __restrict__ hs0, float* __restrict__ cs0,
    u16* __restrict__ hs1, float* __restrict__ cs1, int d)
{
    __shared__ __align__(16) u16 SMEM[73984];   // 147968 B, overlaid per role
    const int tid = threadIdx.x;

    if (blockIdx.x < 32) {
        // =================== rec ===================
        const int L   = blockIdx.x >> 4;
        const int blk = blockIdx.x & 15;
        const int chunk = L ? d - 3 : d - 1;
        if (chunk < 0 || chunk >= NCH) return;
        const u16* xp = (L ? xp1base : xp0base) + (size_t)(chunk & 1) * XPCH;
        const u16* Wf = L ? Whh1f : Whh0f;
        u16*  hs = L ? hs1 : hs0;
        float* cs = L ? cs1 : cs0;
        u16* h0c = h0cbase + (size_t)(chunk & 1) * H0CCH;
        const int init = (chunk == 0);

        u16* WL = SMEM;                                   // 131072 B
        u16 (*hAp)[264] = (u16 (*)[264])(SMEM + 65536);   // [2*16][264]

        const int wave = tid >> 6, lane = tid & 63;
        const int ml   = lane & 15, q = lane >> 4;
        const int ub   = wave * 32;
        const int bb0  = blk * 16;

        // frag-order W base for this wave/lane: all accesses lane-contiguous
        const u16* wfb = Wf + (size_t)wave * 32768 + lane * 8;

        // stage W k-frags 0-1 into LDS (contiguous 1KB per wave inst)
        const int wlb = (wave * 1024 + lane) * 8;
        #pragma unroll
        for (int kf = 0; kf < 2; ++kf)
            #pragma unroll
            for (int f = 0; f < 8; ++f)
                *(bf16x8*)&WL[wlb + (kf * 8 + f) * 512] =
                    *(const bf16x8*)(wfb + (kf * 8 + f) * 512);

        // W k-frags 2-6 persistent in registers (160 regs)
        bf16x8 wreg[5][8];
        #pragma unroll
        for (int kf = 2; kf < 7; ++kf)
            #pragma unroll
            for (int f = 0; f < 8; ++f)
                wreg[kf - 2][f] = *(const bf16x8*)(wfb + (kf * 8 + f) * 512);

        float c_[8];
        if (init) {
            for (int i = tid; i < 16 * 264; i += 512) ((u16*)hAp)[i] = 0;
            #pragma unroll
            for (int i = 0; i < 8; ++i) c_[i] = 0.f;
        } else {
            int m = tid >> 5, j0 = (tid & 31) * 8;
            *(bf16x8*)&hAp[m][j0] = *(const bf16x8*)&hs[(size_t)(bb0 + m) * 256 + j0];
            #pragma unroll
            for (int s = 0; s < 2; ++s)
                #pragma unroll
                for (int r = 0; r < 4; ++r)
                    c_[s * 4 + r] = cs[(size_t)(bb0 + q * 4 + r) * 256 + ub + s * 16 + ml];
        }

        // xp: [t16+blk][gi][tid][8] -> per-gi contiguous 1KB per wave inst
        const u16* xpt = xp + (size_t)blk * 16384 + (size_t)tid * 8;
        const int m_st = tid >> 5;
        const int j_st = (tid & 31) * 8;

        __syncthreads();

        // prologue: xv(0)
        bf16x8 xv[4];
        #pragma unroll
        for (int gi = 0; gi < 4; ++gi)
            xv[gi] = *(const bf16x8*)(xpt + gi * 4096);

        for (int t = 0; t < TCH; ++t) {
            const int br = t & 1, bw = br ^ 1;

            f32x4 acc[4][2];
            #pragma unroll
            for (int gi = 0; gi < 4; ++gi)
                #pragma unroll
                for (int s = 0; s < 2; ++s)
                    acc[gi][s] = (f32x4)0.f;

            #pragma unroll
            for (int kf = 0; kf < 2; ++kf) {
                bf16x8 a = *(const bf16x8*)&hAp[br * 16 + ml][kf * 32 + q * 8];
                #pragma unroll
                for (int f = 0; f < 8; ++f) {
                    bf16x8 b = *(const bf16x8*)&WL[wlb + (kf * 8 + f) * 512];
                    acc[f >> 1][f & 1] = __builtin_amdgcn_mfma_f32_16x16x32_bf16(
                        a, b, acc[f >> 1][f & 1], 0, 0, 0);
                }
            }
            #pragma unroll
            for (int kf = 2; kf < 7; ++kf) {
                bf16x8 a = *(const bf16x8*)&hAp[br * 16 + ml][kf * 32 + q * 8];
                #pragma unroll
                for (int f = 0; f < 8; ++f)
                    acc[f >> 1][f & 1] = __builtin_amdgcn_mfma_f32_16x16x32_bf16(
                        a, wreg[kf - 2][f], acc[f >> 1][f & 1], 0, 0, 0);
            }
            // kf7 streamed from L2 (t-invariant addresses; compiler hoists)
            {
                bf16x8 a = *(const bf16x8*)&hAp[br * 16 + ml][7 * 32 + q * 8];
                #pragma unroll
                for (int f = 0; f < 8; ++f) {
                    bf16x8 b = *(const bf16x8*)(wfb + (7 * 8 + f) * 512);
                    acc[f >> 1][f & 1] = __builtin_amdgcn_mfma_f32_16x16x32_bf16(
                        a, b, acc[f >> 1][f & 1], 0, 0, 0);
                }
            }

            // activations + cell update (xv prefetched a full step ago)
            #pragma unroll
            for (int s = 0; s < 2; ++s) {
                const int j = ub + s * 16 + ml;
                float hv[4];
                #pragma unroll
                for (int r = 0; r < 4; ++r) {
                    float ig = sigm(acc[0][s][r] + bf2f((u16)xv[0][s * 4 + r]));
                    float fg = sigm(acc[1][s][r] + bf2f((u16)xv[1][s * 4 + r]));
                    float gg = tanh_f(acc[2][s][r] + bf2f((u16)xv[2][s * 4 + r]));
                    float og = sigm(acc[3][s][r] + bf2f((u16)xv[3][s * 4 + r]));
                    float cc = fg * c_[s * 4 + r] + ig * gg;
                    c_[s * 4 + r] = cc;
                    hv[r] = og * tanh_f(cc);
                }
                unsigned p01, p23;
                asm("v_cvt_pk_bf16_f32 %0, %1, %2" : "=v"(p01) : "v"(hv[0]), "v"(hv[1]));
                asm("v_cvt_pk_bf16_f32 %0, %1, %2" : "=v"(p23) : "v"(hv[2]), "v"(hv[3]));
                hAp[bw * 16 + q * 4 + 0][j] = (u16)p01;
                hAp[bw * 16 + q * 4 + 1][j] = (u16)(p01 >> 16);
                hAp[bw * 16 + q * 4 + 2][j] = (u16)p23;
                hAp[bw * 16 + q * 4 + 3][j] = (u16)(p23 >> 16);
                if (L == 1 && chunk == NCH - 1 && t == TCH - 1) {
                    #pragma unroll
                    for (int r = 0; r < 4; ++r)
                        hlast[(size_t)(bb0 + q * 4 + r) * 256 + j] = hv[r];
                }
            }
            // reload xv for t+1 (last step reads past chunk -- mapped, unused)
            xpt += XPSTEP;
            #pragma unroll
            for (int gi = 0; gi < 4; ++gi)
                xv[gi] = *(const bf16x8*)(xpt + gi * 4096);

            // publish h(t+1): only hA ds_writes gate the barrier
            asm volatile("s_waitcnt lgkmcnt(0)\n\ts_barrier" ::: "memory");

            if (L == 0)
                *(bf16x8*)&h0c[((size_t)t * 256 + bb0 + m_st) * 256 + j_st] =
                    *(const bf16x8*)&hAp[bw * 16 + m_st][j_st];
        }

        // persist state (TCH even -> final h is in buf 0)
        #pragma unroll
        for (int s = 0; s < 2; ++s)
            #pragma unroll
            for (int r = 0; r < 4; ++r)
                cs[(size_t)(bb0 + q * 4 + r) * 256 + ub + s * 16 + ml] = c_[s * 4 + r];
        {
            int m = tid >> 5, j0 = (tid & 31) * 8;
            *(bf16x8*)&hs[(size_t)(bb0 + m) * 256 + j0] = *(const bf16x8*)&hAp[m][j0];
        }
        return;
    }

    // =================== gemm (A: xp0 from x; B: xp1 from h0c) ===================
    const int role = (blockIdx.x < 288) ? 0 : 1;
    const int bid  = blockIdx.x - (role ? 288 : 32);
    const int chunk = role ? d - 2 : d;
    if (chunk < 0 || chunk >= NCH) return;

    const int K = role ? 256 : 64;
    const u16* Wp = role ? Wih1b : Wih0b;
    const float* bias = role ? bias1 : bias0;
    u16* out = (role ? xp1base : xp0base) + (size_t)(chunk & 1) * XPCH;
    const u16* A1 = h0cbase + (size_t)(chunk & 1) * H0CCH;   // role B source

    u16 (*As)[40] = (u16 (*)[40])SMEM;            // [128][40]
    u16 (*Bs)[40] = (u16 (*)[40])(SMEM + 5120);   // [256][40]

    const int mb = bid >> 2, nb = bid & 3;
    const int n0 = nb * 256;
    const int wave = tid >> 6, lane = tid & 63;
    const int wm = wave >> 2, wn = wave & 3;      // 2 x 4 wave grid -> 128x256 tile
    const int ml = lane & 15, q = lane >> 4;
    const int tloc = mb >> 1;
    const int bbas = (mb & 1) * 128;
    const int tt = role ? tloc : chunk * TCH + tloc;

    f32x4 acc[4][4];
    #pragma unroll
    for (int mi = 0; mi < 4; ++mi)
        #pragma unroll
        for (int ni = 0; ni < 4; ++ni)
            acc[mi][ni] = (f32x4)0.f;

    const int nk = K >> 5;
    for (int kt = 0; kt < nk; ++kt) {
        __syncthreads();
        {
            int row = tid >> 2, kb = tid & 3;
            if (role) {
                *(uint4*)&As[row][kb * 8] = *(const uint4*)(
                    A1 + (size_t)tt * 65536 + (size_t)(bbas + row) * 256 + kt * 32 + kb * 8);
            } else {
                const float* xs = x + (size_t)(bbas + row) * 32768 + (size_t)tt * 64
                                    + kt * 32 + kb * 8;
                float4 fa = *(const float4*)xs;
                float4 fb = *(const float4*)(xs + 4);
                uint4 v;
                v.x = f2bf(fa.x) | ((unsigned)f2bf(fa.y) << 16);
                v.y = f2bf(fa.z) | ((unsigned)f2bf(fa.w) << 16);
                v.z = f2bf(fb.x) | ((unsigned)f2bf(fb.y) << 16);
                v.w = f2bf(fb.z) | ((unsigned)f2bf(fb.w) << 16);
                *(uint4*)&As[row][kb * 8] = v;
            }
            #pragma unroll
            for (int i = 0; i < 2; ++i) {
                int c2 = tid + i * 512, r2 = c2 >> 2, k2 = c2 & 3;
                *(uint4*)&Bs[r2][k2 * 8] = *(const uint4*)(
                    Wp + (size_t)(n0 + r2) * K + kt * 32 + k2 * 8);
            }
        }
        __syncthreads();
        bf16x8 af[4], bfr[4];
        #pragma unroll
        for (int mi = 0; mi < 4; ++mi)
            af[mi] = *(const bf16x8*)&As[wm * 64 + mi * 16 + ml][q * 8];
        #pragma unroll
        for (int ni = 0; ni < 4; ++ni)
            bfr[ni] = *(const bf16x8*)&Bs[wn * 64 + ni * 16 + ml][q * 8];
        #pragma unroll
        for (int mi = 0; mi < 4; ++mi)
            #pragma unroll
            for (int ni = 0; ni < 4; ++ni)
                acc[mi][ni] = __builtin_amdgcn_mfma_f32_16x16x32_bf16(
                    af[mi], bfr[ni], acc[mi][ni], 0, 0, 0);
    }

    // epilogue -> xp (R11 layout, VERIFIED form):
    // el = ((tloc*16+blk2)*4+gi)*512*8 ... = ((x)*512 + tid_r)*8 + s*4 + rr
    #pragma unroll
    for (int ni = 0; ni < 4; ++ni) {
        int gc = n0 + wn * 64 + ni * 16 + ml;
        int gi = gc >> 8, u = gc & 255;
        int wv = u >> 5, s = (u >> 4) & 1, mlr = u & 15;
        float bv = bias[gc];
        #pragma unroll
        for (int mi = 0; mi < 4; ++mi) {
            int rowbase = bbas + wm * 64 + mi * 16;        // multiple of 16
            int blk2 = rowbase >> 4;
            size_t el0 = ((size_t)((tloc * 16 + blk2) * 4 + gi) * 512
                          + wv * 64 + q * 16 + mlr) * 8 + s * 4;
            #pragma unroll
            for (int rr = 0; rr < 4; ++rr)
                out[el0 + rr] = f2bf(acc[mi][ni][rr] + bv);
        }
    }
}

// ---------------- FC head ----------------
__global__ void fc_k(const float* __restrict__ h, const float* __restrict__ w,
                     const float* __restrict__ b, float* __restrict__ out)
{
    int bb = blockIdx.x, lane = threadIdx.x;
    float s = 0.f;
    for (int j = lane; j < 256; j += 64) s += h[bb * 256 + j] * w[j];
    #pragma unroll
    for (int off = 32; off > 0; off >>= 1) s += __shfl_down(s, off);
    if (lane == 0) out[bb] = s + b[0];
}

extern "C" void kernel_launch(void* const* d_in, const int* in_sizes, int n_in,
                              void* d_out, int out_size, void* d_ws, size_t ws_size,
                              hipStream_t stream)
{
    const float* x    = (const float*)d_in[0];
    const float* Wih0 = (const float*)d_in[1];
    const float* Whh0 = (const float*)d_in[2];
    const float* bih0 = (const float*)d_in[3];
    const float* bhh0 = (const float*)d_in[4];
    const float* Wih1 = (const float*)d_in[5];
    const float* Whh1 = (const float*)d_in[6];
    const float* bih1 = (const float*)d_in[7];
    const float* bhh1 = (const float*)d_in[8];
    const float* fcw  = (const float*)d_in[9];
    const float* fcb  = (const float*)d_in[10];
    float* out = (float*)d_out;

    // workspace layout, total ~75.6 MB
    char* ws = (char*)d_ws;
    u16*   xp0b  = (u16*)(ws);                  // 33554432  (2 chunks)
    u16*   xp1b  = (u16*)(ws + 33554432);       // 33554432  (2 chunks)
    u16*   h0cb  = (u16*)(ws + 67108864);       //  8388608  (2 chunks)
    u16*   Wih0b = (u16*)(ws + 75497472);       //   131072
    u16*   Whh0b = (u16*)(ws + 75628544);       //   524288
    u16*   Wih1b = (u16*)(ws + 76152832);       //   524288
    u16*   Whh1b = (u16*)(ws + 76677120);       //   524288
    float* bias0 = (float*)(ws + 77201408);     //     4096
    float* bias1 = (float*)(ws + 77205504);     //     4096
    u16*   hs0   = (u16*)(ws + 77209600);       //   131072
    float* cs0   = (float*)(ws + 77340672);     //   262144
    u16*   hs1   = (u16*)(ws + 77602816);       //   131072
    float* cs1   = (float*)(ws + 77733888);     //   262144
    float* h1l   = (float*)(ws + 77996032);     //   262144
    u16*   Whh0f = (u16*)(ws + 78258176);       //   524288  frag-order W
    u16*   Whh1f = (u16*)(ws + 78782464);       //   524288

    k_conv<<<256,  256, 0, stream>>>(Wih0, Wih0b, 65536);
    k_conv<<<1024, 256, 0, stream>>>(Whh0, Whh0b, 262144);
    k_conv<<<1024, 256, 0, stream>>>(Wih1, Wih1b, 262144);
    k_conv<<<1024, 256, 0, stream>>>(Whh1, Whh1b, 262144);
    k_bias<<<4, 256, 0, stream>>>(bih0, bhh0, bias0, 1024);
    k_bias<<<4, 256, 0, stream>>>(bih1, bhh1, bias1, 1024);
    k_wshuf<<<512, 64, 0, stream>>>(Whh0b, Whh0f);
    k_wshuf<<<512, 64, 0, stream>>>(Whh1b, Whh1f);

    for (int d = 0; d <= NCH + 2; ++d)   // d = 0..18
        mega<<<544, 512, 0, stream>>>(x, Wih0b, Whh0f, Wih1b, Whh1f,
                                      bias0, bias1, xp0b, xp1b, h0cb, h1l,
                                      hs0, cs0, hs1, cs1, d);
    fc_k<<<256, 64, 0, stream>>>(h1l, fcw, fcb, out);
}